// Round 8
// baseline (190.965 us; speedup 1.0000x reference)
//
#include <hip/hip_runtime.h>

// YOLO-v1 loss, N=4096, S=14, 30 ch/cell. ~176 MB in, 5 floats out.
// History: R5 57us (drain-phased); R7 54us (one-shot, uncoalesced); R8 67us
// (compiler sank pipeline; but raw rate 2.64 TB/s UNGATED); R9 75us (spill);
// R10 57us (DMA+counted-vmcnt pipeline, gated, 1.93 TB/s raw); R12 = R10 +
// non-temporal reads -> ~45us (total 198.6->184.8). Rate now ~3.0 TB/s vs
// 6.3-6.8 proven by fill/copy. Stall arithmetic: rate-bound, not latency
// (MLP ~10x sufficient). Remaining suspect: 15%-density gated tcls/tbox
// reads are isolated 128-256B DRAM islands (activate-bound, 3-5x worse than
// streaming) -- note R8's ungated stream out-rated R10's gated one.
// R13: single-variable A/B vs R12 -- UNGATE the loads (tcls/tbox always
// loaded, pure sequential streams, +43 MB), obj still gates the MATH.
// Everything else byte-identical to R12 (NT policy, DMA, WAIT8 discipline).

#define CELLS   802816              // 4096 * 14 * 14
#define THREADS 256
#define NBLK    1024                // 4 blocks/CU resident
#define NWAVES  (NBLK * 4)          // 4096
#define CHUNK   32
#define CHUNKS  (CELLS / CHUNK)     // 25088 -> 6 or 7 chunks per wave
#define MAXSLOT 7
#define L_COORD 5.0f
#define L_NOOBJ 0.5f

typedef float f32x4 __attribute__((ext_vector_type(4)));

// pred DMA with NT cache policy (aux=2 on gfx950)
#define GL16(gsrc, ldst)                                                      \
    __builtin_amdgcn_global_load_lds(                                         \
        (const __attribute__((address_space(1))) void*)(gsrc),                \
        (__attribute__((address_space(3))) void*)(ldst), 16, 0, 2)

// register load, non-temporal, invisible to scheduler heuristics
#define ALOAD16(dst, ptr)                                                     \
    asm volatile("global_load_dwordx4 %0, %1, off nt" : "=v"(dst) : "v"(ptr))

#define WAIT8  asm volatile("s_waitcnt vmcnt(8)" ::: "memory")
#define WAIT0  asm volatile("s_waitcnt vmcnt(0)" ::: "memory")

// issue chunk (cn): 4 pred DMA ops into LDS buffer bufn (no dest regs),
// 3 tcls + 1 tbox asm loads (UNGATED, sequential) -> 8 VMEM ops per wave.
#define ISSUE(cn, T0, T1, T2, Bx, bufn) do {                                  \
    const f32x4* p4_ = (const f32x4*)pred + (size_t)(cn) * 240;               \
    const f32x4* t4_ = (const f32x4*)tcls + (size_t)(cn) * 160;               \
    GL16(p4_ + lane,       (bufn));                                           \
    GL16(p4_ + 64 + lane,  (bufn) + 256);                                     \
    GL16(p4_ + 128 + lane, (bufn) + 512);                                     \
    if (lane < 48) GL16(p4_ + 192 + lane, (bufn) + 768);                      \
    ALOAD16(T0, t4_ + lane);                                                  \
    ALOAD16(T1, t4_ + i1);                                                    \
    if (lane < 32) ALOAD16(T2, t4_ + i2);                                     \
    ALOAD16(Bx, (const f32x4*)tbox + (size_t)(cn) * CHUNK + bcell);           \
  } while (0)

#define COMPUTE(opk, T0, T1, T2, Bx, sg) do {                                 \
    float cl_ = 0.f;                                                          \
    if ((opk) & 1) {                                                          \
      const float2 a_ = *(const float2*)&(sg)[cc0 * 30 + 10 + ch0];           \
      const float2 b_ = *(const float2*)&(sg)[cc0 * 30 + 12 + ch0];           \
      float d0_ = a_.x - T0.x, d1_ = a_.y - T0.y;                             \
      float d2_ = b_.x - T0.z, d3_ = b_.y - T0.w;                             \
      cl_ += d0_*d0_ + d1_*d1_ + d2_*d2_ + d3_*d3_;                           \
    }                                                                         \
    if ((opk) & 2) {                                                          \
      const float2 a_ = *(const float2*)&(sg)[cc1 * 30 + 10 + ch1];           \
      const float2 b_ = *(const float2*)&(sg)[cc1 * 30 + 12 + ch1];           \
      float d0_ = a_.x - T1.x, d1_ = a_.y - T1.y;                             \
      float d2_ = b_.x - T1.z, d3_ = b_.y - T1.w;                             \
      cl_ += d0_*d0_ + d1_*d1_ + d2_*d2_ + d3_*d3_;                           \
    }                                                                         \
    if ((lane < 32) && ((opk) & 4)) {                                         \
      const float2 a_ = *(const float2*)&(sg)[cc2 * 30 + 10 + ch2];           \
      const float2 b_ = *(const float2*)&(sg)[cc2 * 30 + 12 + ch2];           \
      float d0_ = a_.x - T2.x, d1_ = a_.y - T2.y;                             \
      float d2_ = b_.x - T2.z, d3_ = b_.y - T2.w;                             \
      cl_ += d0_*d0_ + d1_*d1_ + d2_*d2_ + d3_*d3_;                           \
    }                                                                         \
    acc_cls += cl_;                                                           \
    const float* pp_ = &(sg)[bcell * 30 + box * 5];                           \
    float x_ = pp_[0], y_ = pp_[1], w_ = pp_[2], h_ = pp_[3], cf_ = pp_[4];   \
    const bool ox_ = ((opk) & 8) != 0;                                        \
    if (!ox_) acc_noobj += cf_ * cf_;                                         \
    float txc_ = Bx.x * invS, tyc_ = Bx.y * invS;                             \
    float tx1_ = txc_ - 0.5f * Bx.z, ty1_ = tyc_ - 0.5f * Bx.w;               \
    float tx2_ = txc_ + 0.5f * Bx.z, ty2_ = tyc_ + 0.5f * Bx.w;               \
    float ta_  = (tx2_ - tx1_) * (ty2_ - ty1_);                               \
    float ax1_ = x_ * invS - 0.5f * w_, ay1_ = y_ * invS - 0.5f * h_;         \
    float ax2_ = x_ * invS + 0.5f * w_, ay2_ = y_ * invS + 0.5f * h_;         \
    float a1_  = (ax2_ - ax1_) * (ay2_ - ay1_);                               \
    float iw_  = fmaxf(fminf(ax2_, tx2_) - fmaxf(ax1_, tx1_), 0.f);           \
    float ih_  = fmaxf(fminf(ay2_, ty2_) - fmaxf(ay1_, ty1_), 0.f);           \
    float in_  = iw_ * ih_;                                                   \
    float iou_ = in_ / (a1_ + ta_ - in_);                                     \
    float iouo_ = __shfl_xor(iou_, 1);                                        \
    bool win_ = (box == 0) ? (iou_ > iouo_) : !(iouo_ > iou_);                \
    if (win_ && ox_) {                                                        \
      float dx_ = x_ - Bx.x, dy_ = y_ - Bx.y;                                 \
      float dw_ = sqrtf(w_) - sqrtf(Bx.z);                                    \
      float dh_ = sqrtf(h_) - sqrtf(Bx.w);                                    \
      acc_reg  += dx_*dx_ + dy_*dy_ + dw_*dw_ + dh_*dh_;                      \
      float dc_ = cf_ - iou_;                                                 \
      acc_cont += dc_ * dc_;                                                  \
    }                                                                         \
  } while (0)

// slot s: issue chunk s+1 into the "next" set/buffer, counted-wait so
// chunk s's 8 ops are drained (s+1's stay in flight), compute chunk s.
#define SLOT(s, T0c,T1c,T2c,Bc, T0n,T1n,T2n,Bn, bufc, bufn) do {              \
    const int c_ = w0 + (s) * NWAVES;                                         \
    if (c_ < CHUNKS) {                                                        \
      const int cn_ = c_ + NWAVES;                                            \
      if (cn_ < CHUNKS) {                                                     \
        ISSUE(cn_, T0n, T1n, T2n, Bn, bufn);                                  \
        WAIT8;                                                                \
      } else {                                                                \
        WAIT0;                                                                \
      }                                                                       \
      __builtin_amdgcn_sched_barrier(0);                                      \
      COMPUTE(opack[(s)], T0c, T1c, T2c, Bc, bufc);                           \
    }                                                                         \
  } while (0)

__global__ __launch_bounds__(THREADS, 2) void yolo_main(
    const float* __restrict__ pred,    // [CELLS][30]
    const float* __restrict__ tbox,    // [CELLS][4]
    const float* __restrict__ tcls,    // [CELLS][20]
    const int*   __restrict__ objmap,  // [CELLS]
    float4*      __restrict__ part)    // [NBLK]
{
    __shared__ float lds[4 * 1920];    // per wave: 2 buffers x 960 floats
    __shared__ float red[4][4];

    const int tid  = threadIdx.x;
    const int wv   = tid >> 6;
    const int lane = tid & 63;
    float* buf0 = &lds[wv * 1920];
    float* buf1 = buf0 + 960;

    // cls-pass lane->piece mapping (piece i: cell = i/5, ch = (i%5)*4)
    const int cc0 = lane / 5,   ch0 = (lane - cc0 * 5) * 4;
    const int i1  = lane + 64;
    const int cc1 = i1 / 5,     ch1 = (i1 - cc1 * 5) * 4;
    const int i2  = lane + 128;
    const int cc2 = (lane < 32) ? (i2 / 5) : 0;
    const int ch2 = (lane < 32) ? (i2 - cc2 * 5) * 4 : 0;
    const int bcell = lane >> 1;       // box pass: 2 lanes per cell
    const int box   = lane & 1;
    const float invS = 1.0f / 14.0f;

    float acc_reg = 0.f, acc_cont = 0.f, acc_noobj = 0.f, acc_cls = 0.f;

    const int w0 = blockIdx.x * 4 + wv;   // this wave's first chunk

    // ---- obj prefetch for ALL slots, packed (math gating only now) ----
    int opack[MAXSLOT + 1];
    #pragma unroll
    for (int s = 0; s < MAXSLOT; ++s) {
        const int c = w0 + s * NWAVES;
        int v = 0;
        if (c < CHUNKS) {
            const int* ob = objmap + (size_t)c * CHUNK;
            v  = ob[cc0]  ? 1 : 0;
            v |= ob[cc1]  ? 2 : 0;
            v |= ob[cc2]  ? 4 : 0;
            v |= ob[bcell]? 8 : 0;
        }
        opack[s] = v;
    }
    opack[MAXSLOT] = 0;

    // ---- two named prefetch register sets (32 VGPR total) ----
    f32x4 TA0, TA1, TA2, BA;
    f32x4 TB0, TB1, TB2, BB;

    // prologue: chunk w0 into set A / buf0 (w0 < NWAVES <= CHUNKS always)
    ISSUE(w0, TA0, TA1, TA2, BA, buf0);
    __builtin_amdgcn_sched_barrier(0);

    SLOT(0, TA0,TA1,TA2,BA, TB0,TB1,TB2,BB, buf0, buf1);
    SLOT(1, TB0,TB1,TB2,BB, TA0,TA1,TA2,BA, buf1, buf0);
    SLOT(2, TA0,TA1,TA2,BA, TB0,TB1,TB2,BB, buf0, buf1);
    SLOT(3, TB0,TB1,TB2,BB, TA0,TA1,TA2,BA, buf1, buf0);
    SLOT(4, TA0,TA1,TA2,BA, TB0,TB1,TB2,BB, buf0, buf1);
    SLOT(5, TB0,TB1,TB2,BB, TA0,TA1,TA2,BA, buf1, buf0);
    SLOT(6, TA0,TA1,TA2,BA, TB0,TB1,TB2,BB, buf0, buf1);

    // ---- final reduction ----
    #pragma unroll
    for (int off = 32; off > 0; off >>= 1) {
        acc_reg   += __shfl_down(acc_reg,   off);
        acc_cont  += __shfl_down(acc_cont,  off);
        acc_noobj += __shfl_down(acc_noobj, off);
        acc_cls   += __shfl_down(acc_cls,   off);
    }
    if (lane == 0) {
        red[wv][0] = acc_reg;
        red[wv][1] = acc_cont;
        red[wv][2] = acc_noobj;
        red[wv][3] = acc_cls;
    }
    __syncthreads();
    if (tid == 0) {
        float4 p;
        p.x = red[0][0] + red[1][0] + red[2][0] + red[3][0];
        p.y = red[0][1] + red[1][1] + red[2][1] + red[3][1];
        p.z = red[0][2] + red[1][2] + red[2][2] + red[3][2];
        p.w = red[0][3] + red[1][3] + red[2][3] + red[3][3];
        part[blockIdx.x] = p;
    }
}

__global__ __launch_bounds__(1024) void yolo_reduce(
    const float4* __restrict__ part, float* __restrict__ out)
{
    __shared__ float red[16][4];
    float r = 0.f, c = 0.f, n = 0.f, cl = 0.f;
    for (int i = threadIdx.x; i < NBLK; i += 1024) {   // exactly 1 load
        float4 p = part[i];
        r += p.x; c += p.y; n += p.z; cl += p.w;
    }
    #pragma unroll
    for (int off = 32; off > 0; off >>= 1) {
        r  += __shfl_down(r,  off);
        c  += __shfl_down(c,  off);
        n  += __shfl_down(n,  off);
        cl += __shfl_down(cl, off);
    }
    const int wave = threadIdx.x >> 6, lane = threadIdx.x & 63;
    if (lane == 0) {
        red[wave][0] = r; red[wave][1] = c; red[wave][2] = n; red[wave][3] = cl;
    }
    __syncthreads();
    if (threadIdx.x == 0) {
        float R = 0.f, C = 0.f, Nn = 0.f, Cl = 0.f;
        #pragma unroll
        for (int w = 0; w < 16; ++w) {
            R += red[w][0]; C += red[w][1]; Nn += red[w][2]; Cl += red[w][3];
        }
        const float invN = 1.0f / 4096.0f;
        float reg   = L_COORD * R  * invN;
        float cont  =           C  * invN;
        float noobj = L_NOOBJ * Nn * invN;
        float cls   =           Cl * invN;
        out[0] = reg + cont + noobj + cls;
        out[1] = reg;
        out[2] = cont;
        out[3] = noobj;
        out[4] = cls;
    }
}

extern "C" void kernel_launch(void* const* d_in, const int* in_sizes, int n_in,
                              void* d_out, int out_size, void* d_ws, size_t ws_size,
                              hipStream_t stream) {
    const float* pred   = (const float*)d_in[0];
    const float* tbox   = (const float*)d_in[1];
    const float* tcls   = (const float*)d_in[2];
    const int*   objmap = (const int*)  d_in[3];
    float4* part = (float4*)d_ws;      // NBLK * 16 B = 16 KB, every slot written
    float*  out  = (float*)d_out;

    yolo_main<<<NBLK, THREADS, 0, stream>>>(pred, tbox, tcls, objmap, part);
    yolo_reduce<<<1, 1024, 0, stream>>>(part, out);
}

// Round 9
// 183.321 us; speedup vs baseline: 1.0417x; 1.0417x over previous
//
#include <hip/hip_runtime.h>

// YOLO-v1 loss, N=4096, S=14, 30 ch/cell. ~176 MB in, 5 floats out.
// History: R5 57us (drain-phased); R7 54us (one-shot MLP); R8 67us (compiler
// sank pipeline); R9 75us (allocator spilled pipeline); R10 57us (DMA +
// counted-vmcnt pipeline, gated); R12 = R10 + non-temporal reads -> ~45us,
// total 184.8 (BEST). R13 A/B (ungated loads): 191.0 -> scatter theory
// refuted, bytes dominate, gating stays.
// R14 = R12 verbatim revert. Probes complete: 4 structures, concurrency,
// register residency, cache policy (NT +12us real), scatter-vs-bytes.
// Demand ~133 MB is within ~15% of the packed-layout floor (120B rows ->
// box-only still touches ~104B/row of sectors). Service rate ~3.0 TB/s for
// this mixed gated-read pattern; six orthogonal probes bracket it.

#define CELLS   802816              // 4096 * 14 * 14
#define THREADS 256
#define NBLK    1024                // 4 blocks/CU resident
#define NWAVES  (NBLK * 4)          // 4096
#define CHUNK   32
#define CHUNKS  (CELLS / CHUNK)     // 25088 -> 6 or 7 chunks per wave
#define MAXSLOT 7
#define L_COORD 5.0f
#define L_NOOBJ 0.5f

typedef float f32x4 __attribute__((ext_vector_type(4)));

// pred DMA with NT cache policy (aux=2 on gfx950)
#define GL16(gsrc, ldst)                                                      \
    __builtin_amdgcn_global_load_lds(                                         \
        (const __attribute__((address_space(1))) void*)(gsrc),                \
        (__attribute__((address_space(3))) void*)(ldst), 16, 0, 2)

// register load, non-temporal, invisible to scheduler heuristics
#define ALOAD16(dst, ptr)                                                     \
    asm volatile("global_load_dwordx4 %0, %1, off nt" : "=v"(dst) : "v"(ptr))

#define WAIT8  asm volatile("s_waitcnt vmcnt(8)" ::: "memory")
#define WAIT0  asm volatile("s_waitcnt vmcnt(0)" ::: "memory")

// issue chunk (cn): 4 pred DMA ops into LDS buffer bufn (no dest regs),
// 3 tcls + 1 tbox asm loads (address-selected on gate bits) -> 8 VMEM ops.
#define ISSUE(cn, opk, T0, T1, T2, Bx, bufn) do {                             \
    const f32x4* p4_ = (const f32x4*)pred + (size_t)(cn) * 240;               \
    const f32x4* t4_ = (const f32x4*)tcls + (size_t)(cn) * 160;               \
    GL16(p4_ + lane,       (bufn));                                           \
    GL16(p4_ + 64 + lane,  (bufn) + 256);                                     \
    GL16(p4_ + 128 + lane, (bufn) + 512);                                     \
    if (lane < 48) GL16(p4_ + 192 + lane, (bufn) + 768);                      \
    ALOAD16(T0, t4_ + (((opk) & 1) ? lane : 0));                              \
    ALOAD16(T1, t4_ + (((opk) & 2) ? i1 : 0));                                \
    ALOAD16(T2, t4_ + ((((opk) & 4) && lane < 32) ? i2 : 0));                 \
    ALOAD16(Bx, (const f32x4*)tbox + (size_t)(cn) * CHUNK +                   \
                (((opk) & 8) ? bcell : 0));                                   \
  } while (0)

#define COMPUTE(opk, T0, T1, T2, Bx, sg) do {                                 \
    float cl_ = 0.f;                                                          \
    if ((opk) & 1) {                                                          \
      const float2 a_ = *(const float2*)&(sg)[cc0 * 30 + 10 + ch0];           \
      const float2 b_ = *(const float2*)&(sg)[cc0 * 30 + 12 + ch0];           \
      float d0_ = a_.x - T0.x, d1_ = a_.y - T0.y;                             \
      float d2_ = b_.x - T0.z, d3_ = b_.y - T0.w;                             \
      cl_ += d0_*d0_ + d1_*d1_ + d2_*d2_ + d3_*d3_;                           \
    }                                                                         \
    if ((opk) & 2) {                                                          \
      const float2 a_ = *(const float2*)&(sg)[cc1 * 30 + 10 + ch1];           \
      const float2 b_ = *(const float2*)&(sg)[cc1 * 30 + 12 + ch1];           \
      float d0_ = a_.x - T1.x, d1_ = a_.y - T1.y;                             \
      float d2_ = b_.x - T1.z, d3_ = b_.y - T1.w;                             \
      cl_ += d0_*d0_ + d1_*d1_ + d2_*d2_ + d3_*d3_;                           \
    }                                                                         \
    if ((lane < 32) && ((opk) & 4)) {                                         \
      const float2 a_ = *(const float2*)&(sg)[cc2 * 30 + 10 + ch2];           \
      const float2 b_ = *(const float2*)&(sg)[cc2 * 30 + 12 + ch2];           \
      float d0_ = a_.x - T2.x, d1_ = a_.y - T2.y;                             \
      float d2_ = b_.x - T2.z, d3_ = b_.y - T2.w;                             \
      cl_ += d0_*d0_ + d1_*d1_ + d2_*d2_ + d3_*d3_;                           \
    }                                                                         \
    acc_cls += cl_;                                                           \
    const float* pp_ = &(sg)[bcell * 30 + box * 5];                           \
    float x_ = pp_[0], y_ = pp_[1], w_ = pp_[2], h_ = pp_[3], cf_ = pp_[4];   \
    const bool ox_ = ((opk) & 8) != 0;                                        \
    if (!ox_) acc_noobj += cf_ * cf_;                                         \
    float txc_ = Bx.x * invS, tyc_ = Bx.y * invS;                             \
    float tx1_ = txc_ - 0.5f * Bx.z, ty1_ = tyc_ - 0.5f * Bx.w;               \
    float tx2_ = txc_ + 0.5f * Bx.z, ty2_ = tyc_ + 0.5f * Bx.w;               \
    float ta_  = (tx2_ - tx1_) * (ty2_ - ty1_);                               \
    float ax1_ = x_ * invS - 0.5f * w_, ay1_ = y_ * invS - 0.5f * h_;         \
    float ax2_ = x_ * invS + 0.5f * w_, ay2_ = y_ * invS + 0.5f * h_;         \
    float a1_  = (ax2_ - ax1_) * (ay2_ - ay1_);                               \
    float iw_  = fmaxf(fminf(ax2_, tx2_) - fmaxf(ax1_, tx1_), 0.f);           \
    float ih_  = fmaxf(fminf(ay2_, ty2_) - fmaxf(ay1_, ty1_), 0.f);           \
    float in_  = iw_ * ih_;                                                   \
    float iou_ = in_ / (a1_ + ta_ - in_);                                     \
    float iouo_ = __shfl_xor(iou_, 1);                                        \
    bool win_ = (box == 0) ? (iou_ > iouo_) : !(iouo_ > iou_);                \
    if (win_ && ox_) {                                                        \
      float dx_ = x_ - Bx.x, dy_ = y_ - Bx.y;                                 \
      float dw_ = sqrtf(w_) - sqrtf(Bx.z);                                    \
      float dh_ = sqrtf(h_) - sqrtf(Bx.w);                                    \
      acc_reg  += dx_*dx_ + dy_*dy_ + dw_*dw_ + dh_*dh_;                      \
      float dc_ = cf_ - iou_;                                                 \
      acc_cont += dc_ * dc_;                                                  \
    }                                                                         \
  } while (0)

// slot s: issue chunk s+1 into the "next" set/buffer, counted-wait so
// chunk s's 8 ops are drained (s+1's stay in flight), compute chunk s.
#define SLOT(s, T0c,T1c,T2c,Bc, T0n,T1n,T2n,Bn, bufc, bufn) do {              \
    const int c_ = w0 + (s) * NWAVES;                                         \
    if (c_ < CHUNKS) {                                                        \
      const int cn_ = c_ + NWAVES;                                            \
      if (cn_ < CHUNKS) {                                                     \
        ISSUE(cn_, opack[(s) + 1], T0n, T1n, T2n, Bn, bufn);                  \
        WAIT8;                                                                \
      } else {                                                                \
        WAIT0;                                                                \
      }                                                                       \
      __builtin_amdgcn_sched_barrier(0);                                      \
      COMPUTE(opack[(s)], T0c, T1c, T2c, Bc, bufc);                           \
    }                                                                         \
  } while (0)

__global__ __launch_bounds__(THREADS, 2) void yolo_main(
    const float* __restrict__ pred,    // [CELLS][30]
    const float* __restrict__ tbox,    // [CELLS][4]
    const float* __restrict__ tcls,    // [CELLS][20]
    const int*   __restrict__ objmap,  // [CELLS]
    float4*      __restrict__ part)    // [NBLK]
{
    __shared__ float lds[4 * 1920];    // per wave: 2 buffers x 960 floats
    __shared__ float red[4][4];

    const int tid  = threadIdx.x;
    const int wv   = tid >> 6;
    const int lane = tid & 63;
    float* buf0 = &lds[wv * 1920];
    float* buf1 = buf0 + 960;

    // cls-pass lane->piece mapping (piece i: cell = i/5, ch = (i%5)*4)
    const int cc0 = lane / 5,   ch0 = (lane - cc0 * 5) * 4;
    const int i1  = lane + 64;
    const int cc1 = i1 / 5,     ch1 = (i1 - cc1 * 5) * 4;
    const int i2  = lane + 128;
    const int cc2 = (lane < 32) ? (i2 / 5) : 0;
    const int ch2 = (lane < 32) ? (i2 - cc2 * 5) * 4 : 0;
    const int bcell = lane >> 1;       // box pass: 2 lanes per cell
    const int box   = lane & 1;
    const float invS = 1.0f / 14.0f;

    float acc_reg = 0.f, acc_cont = 0.f, acc_noobj = 0.f, acc_cls = 0.f;

    const int w0 = blockIdx.x * 4 + wv;   // this wave's first chunk

    // ---- obj prefetch for ALL slots, packed (plain C; pre-pipeline) ----
    int opack[MAXSLOT + 1];
    #pragma unroll
    for (int s = 0; s < MAXSLOT; ++s) {
        const int c = w0 + s * NWAVES;
        int v = 0;
        if (c < CHUNKS) {
            const int* ob = objmap + (size_t)c * CHUNK;
            v  = ob[cc0]  ? 1 : 0;
            v |= ob[cc1]  ? 2 : 0;
            v |= ob[cc2]  ? 4 : 0;
            v |= ob[bcell]? 8 : 0;
        }
        opack[s] = v;
    }
    opack[MAXSLOT] = 0;

    // ---- two named prefetch register sets (32 VGPR total) ----
    f32x4 TA0, TA1, TA2, BA;
    f32x4 TB0, TB1, TB2, BB;

    // prologue: chunk w0 into set A / buf0 (w0 < NWAVES <= CHUNKS always)
    ISSUE(w0, opack[0], TA0, TA1, TA2, BA, buf0);
    __builtin_amdgcn_sched_barrier(0);

    SLOT(0, TA0,TA1,TA2,BA, TB0,TB1,TB2,BB, buf0, buf1);
    SLOT(1, TB0,TB1,TB2,BB, TA0,TA1,TA2,BA, buf1, buf0);
    SLOT(2, TA0,TA1,TA2,BA, TB0,TB1,TB2,BB, buf0, buf1);
    SLOT(3, TB0,TB1,TB2,BB, TA0,TA1,TA2,BA, buf1, buf0);
    SLOT(4, TA0,TA1,TA2,BA, TB0,TB1,TB2,BB, buf0, buf1);
    SLOT(5, TB0,TB1,TB2,BB, TA0,TA1,TA2,BA, buf1, buf0);
    SLOT(6, TA0,TA1,TA2,BA, TB0,TB1,TB2,BB, buf0, buf1);

    // ---- final reduction ----
    #pragma unroll
    for (int off = 32; off > 0; off >>= 1) {
        acc_reg   += __shfl_down(acc_reg,   off);
        acc_cont  += __shfl_down(acc_cont,  off);
        acc_noobj += __shfl_down(acc_noobj, off);
        acc_cls   += __shfl_down(acc_cls,   off);
    }
    if (lane == 0) {
        red[wv][0] = acc_reg;
        red[wv][1] = acc_cont;
        red[wv][2] = acc_noobj;
        red[wv][3] = acc_cls;
    }
    __syncthreads();
    if (tid == 0) {
        float4 p;
        p.x = red[0][0] + red[1][0] + red[2][0] + red[3][0];
        p.y = red[0][1] + red[1][1] + red[2][1] + red[3][1];
        p.z = red[0][2] + red[1][2] + red[2][2] + red[3][2];
        p.w = red[0][3] + red[1][3] + red[2][3] + red[3][3];
        part[blockIdx.x] = p;
    }
}

__global__ __launch_bounds__(1024) void yolo_reduce(
    const float4* __restrict__ part, float* __restrict__ out)
{
    __shared__ float red[16][4];
    float r = 0.f, c = 0.f, n = 0.f, cl = 0.f;
    for (int i = threadIdx.x; i < NBLK; i += 1024) {   // exactly 1 load
        float4 p = part[i];
        r += p.x; c += p.y; n += p.z; cl += p.w;
    }
    #pragma unroll
    for (int off = 32; off > 0; off >>= 1) {
        r  += __shfl_down(r,  off);
        c  += __shfl_down(c,  off);
        n  += __shfl_down(n,  off);
        cl += __shfl_down(cl, off);
    }
    const int wave = threadIdx.x >> 6, lane = threadIdx.x & 63;
    if (lane == 0) {
        red[wave][0] = r; red[wave][1] = c; red[wave][2] = n; red[wave][3] = cl;
    }
    __syncthreads();
    if (threadIdx.x == 0) {
        float R = 0.f, C = 0.f, Nn = 0.f, Cl = 0.f;
        #pragma unroll
        for (int w = 0; w < 16; ++w) {
            R += red[w][0]; C += red[w][1]; Nn += red[w][2]; Cl += red[w][3];
        }
        const float invN = 1.0f / 4096.0f;
        float reg   = L_COORD * R  * invN;
        float cont  =           C  * invN;
        float noobj = L_NOOBJ * Nn * invN;
        float cls   =           Cl * invN;
        out[0] = reg + cont + noobj + cls;
        out[1] = reg;
        out[2] = cont;
        out[3] = noobj;
        out[4] = cls;
    }
}

extern "C" void kernel_launch(void* const* d_in, const int* in_sizes, int n_in,
                              void* d_out, int out_size, void* d_ws, size_t ws_size,
                              hipStream_t stream) {
    const float* pred   = (const float*)d_in[0];
    const float* tbox   = (const float*)d_in[1];
    const float* tcls   = (const float*)d_in[2];
    const int*   objmap = (const int*)  d_in[3];
    float4* part = (float4*)d_ws;      // NBLK * 16 B = 16 KB, every slot written
    float*  out  = (float*)d_out;

    yolo_main<<<NBLK, THREADS, 0, stream>>>(pred, tbox, tcls, objmap, part);
    yolo_reduce<<<1, 1024, 0, stream>>>(part, out);
}